// Round 1
// baseline (436.725 us; speedup 1.0000x reference)
//
#include <hip/hip_runtime.h>
#include <math.h>

// Sizes
// N=768 atoms, T=256 tokens, CA=128, CP=16, CZ=128, CS=384, CT=384, H=4, DH=32
// d_out: a_out[256*384]@0, qout[768*384]@98304, c[768*128]@393216, pair[768*768*16]@491520

__device__ __forceinline__ float sigmoidf_(float v) { return 1.f / (1.f + __expf(-v)); }

// ---------------------------------------------------------------------------
// K1: per-atom prep: c0 = ref_pos@W_pos ; x = c0 + r@W_noisy ;
//     c = c0 + LN(s[tok])@W_single ; ca = relu(c)@W_cond_a ; cb = relu(c)@W_cond_b
// grid 768, block 256
__global__ __launch_bounds__(256) void k_prep(
    const float* __restrict__ ref_pos, const float* __restrict__ r,
    const float* __restrict__ s, const float* __restrict__ W_pos,
    const float* __restrict__ W_noisy, const float* __restrict__ ln_s_g,
    const float* __restrict__ ln_s_b, const float* __restrict__ W_single,
    const float* __restrict__ W_cond_a, const float* __restrict__ W_cond_b,
    float* __restrict__ c_out, float* __restrict__ x,
    float* __restrict__ ca, float* __restrict__ cb) {
  int i = blockIdx.x, t = threadIdx.x;
  int tok = i & 255;
  __shared__ float sl[384];
  __shared__ float red[8];
  __shared__ float rc[128];
  float v0 = s[tok * 384 + t];
  float v1 = (t < 128) ? s[tok * 384 + 256 + t] : 0.f;
  float ps = v0 + v1, pq = v0 * v0 + v1 * v1;
#pragma unroll
  for (int o = 1; o < 64; o <<= 1) { ps += __shfl_xor(ps, o); pq += __shfl_xor(pq, o); }
  if ((t & 63) == 0) { red[t >> 6] = ps; red[4 + (t >> 6)] = pq; }
  __syncthreads();
  float mean = (red[0] + red[1] + red[2] + red[3]) * (1.f / 384.f);
  float var = (red[4] + red[5] + red[6] + red[7]) * (1.f / 384.f) - mean * mean;
  float rstd = rsqrtf(var + 1e-5f);
  sl[t] = (v0 - mean) * rstd * ln_s_g[t] + ln_s_b[t];
  if (t < 128) sl[256 + t] = (v1 - mean) * rstd * ln_s_g[256 + t] + ln_s_b[256 + t];
  __syncthreads();
  if (t < 128) {
    float p0 = ref_pos[i * 3], p1 = ref_pos[i * 3 + 1], p2 = ref_pos[i * 3 + 2];
    float c0 = p0 * W_pos[t] + p1 * W_pos[128 + t] + p2 * W_pos[256 + t];
    float r0 = r[i * 3], r1 = r[i * 3 + 1], r2 = r[i * 3 + 2];
    x[i * 128 + t] = c0 + r0 * W_noisy[t] + r1 * W_noisy[128 + t] + r2 * W_noisy[256 + t];
    float acc = c0;
#pragma unroll 4
    for (int k = 0; k < 384; k++) acc += sl[k] * W_single[k * 128 + t];
    c_out[i * 128 + t] = acc;
    rc[t] = fmaxf(acc, 0.f);
  }
  __syncthreads();
  if (t < 32) {
    const float* W = (t < 16) ? W_cond_a : W_cond_b;
    int ch = t & 15;
    float acc = 0.f;
#pragma unroll 4
    for (int k = 0; k < 128; k++) acc += rc[k] * W[k * 16 + ch];
    if (t < 16) ca[i * 16 + ch] = acc; else cb[i * 16 + ch] = acc;
  }
}

// ---------------------------------------------------------------------------
// K2: zp[65536,16] = LN(z)@W_pair  (g folded into weights)
// grid 4096, block 256 (16 z-rows per block)
__global__ __launch_bounds__(256) void k_zp(
    const float* __restrict__ z, const float* __restrict__ ln_z_g,
    const float* __restrict__ ln_z_b, const float* __restrict__ W_pair,
    float* __restrict__ zp) {
  __shared__ float Wg[2048];
  __shared__ float sWg[16], Bc[16];
  __shared__ float zs[16][132];
  int t = threadIdx.x;
  for (int e = t; e < 2048; e += 256) Wg[e] = ln_z_g[e >> 4] * W_pair[e];
  __syncthreads();
  if (t < 16) {
    float sw = 0, bc = 0;
#pragma unroll 4
    for (int k = 0; k < 128; k++) { sw += Wg[k * 16 + t]; bc += ln_z_b[k] * W_pair[k * 16 + t]; }
    sWg[t] = sw; Bc[t] = bc;
  }
  int row = t >> 4, kk = (t & 15) * 8;
  long base = ((long)blockIdx.x * 16 + row) * 128 + kk;
  float4 a = *(const float4*)&z[base];
  float4 b = *(const float4*)&z[base + 4];
  *(float4*)&zs[row][kk] = a;
  *(float4*)&zs[row][kk + 4] = b;
  float ps = a.x + a.y + a.z + a.w + b.x + b.y + b.z + b.w;
  float pq = a.x * a.x + a.y * a.y + a.z * a.z + a.w * a.w +
             b.x * b.x + b.y * b.y + b.z * b.z + b.w * b.w;
#pragma unroll
  for (int o = 1; o < 16; o <<= 1) { ps += __shfl_xor(ps, o); pq += __shfl_xor(pq, o); }
  float m = ps * (1.f / 128.f);
  float rstd = rsqrtf(pq * (1.f / 128.f) - m * m + 1e-5f);
  __syncthreads();
  int ch = t & 15;
  float dotv = 0.f;
#pragma unroll 8
  for (int k = 0; k < 128; k++) dotv += zs[row][k] * Wg[k * 16 + ch];
  zp[((long)blockIdx.x * 16 + row) * 16 + ch] = rstd * (dotv - m * sWg[ch]) + Bc[ch];
}

// ---------------------------------------------------------------------------
// K3: pair tensor + MLP + window LN16 -> pnrm
// grid 2304 (i*3+jb), block 256 (one j each)
__global__ __launch_bounds__(256) void k_pair(
    const float* __restrict__ ref_pos, const int* __restrict__ uid,
    const float* __restrict__ Wpo, const float* __restrict__ Wisd,
    const float* __restrict__ Wmask, const float* __restrict__ W1,
    const float* __restrict__ W2, const float* __restrict__ W3,
    const float* __restrict__ zp, const float* __restrict__ ca,
    const float* __restrict__ cb, float* __restrict__ pair_out,
    float* __restrict__ pnrm) {
  int i = blockIdx.x / 3, jb = blockIdx.x % 3, t = threadIdx.x;
  int j = jb * 256 + t;
  __shared__ float w1[256], w2[256], w3[256];
  __shared__ float wpo[48], wisd[16], wmask[16], cai[16];
  w1[t] = W1[t]; w2[t] = W2[t]; w3[t] = W3[t];
  if (t < 48) wpo[t] = Wpo[t];
  if (t < 16) { wisd[t] = Wisd[t]; wmask[t] = Wmask[t]; cai[t] = ca[i * 16 + t]; }
  __syncthreads();
  float d0 = ref_pos[i * 3] - ref_pos[j * 3];
  float d1 = ref_pos[i * 3 + 1] - ref_pos[j * 3 + 1];
  float d2 = ref_pos[i * 3 + 2] - ref_pos[j * 3 + 2];
  float mask = (uid[i] == uid[j]) ? 1.f : 0.f;
  float inv = 1.f / (1.f + d0 * d0 + d1 * d1 + d2 * d2);
  float zb[16];
  {
    const float4* zpv = (const float4*)&zp[(((i & 255) << 8) + t) * 16];
    const float4* cbv = (const float4*)&cb[j * 16];
    float4 q0 = zpv[0], q1 = zpv[1], q2 = zpv[2], q3 = zpv[3];
    float4 b0 = cbv[0], b1 = cbv[1], b2 = cbv[2], b3 = cbv[3];
    zb[0] = q0.x + b0.x; zb[1] = q0.y + b0.y; zb[2] = q0.z + b0.z; zb[3] = q0.w + b0.w;
    zb[4] = q1.x + b1.x; zb[5] = q1.y + b1.y; zb[6] = q1.z + b1.z; zb[7] = q1.w + b1.w;
    zb[8] = q2.x + b2.x; zb[9] = q2.y + b2.y; zb[10] = q2.z + b2.z; zb[11] = q2.w + b2.w;
    zb[12] = q3.x + b3.x; zb[13] = q3.y + b3.y; zb[14] = q3.z + b3.z; zb[15] = q3.w + b3.w;
  }
  float p[16];
#pragma unroll
  for (int c = 0; c < 16; c++)
    p[c] = mask * (d0 * wpo[c] + d1 * wpo[16 + c] + d2 * wpo[32 + c] + inv * wisd[c] + wmask[c])
           + zb[c] + cai[c];
  float t1[16], t2[16];
#pragma unroll
  for (int c = 0; c < 16; c++) t1[c] = fmaxf(p[c], 0.f);
#pragma unroll
  for (int c = 0; c < 16; c++) {
    float a = 0.f;
#pragma unroll
    for (int k = 0; k < 16; k++) a += t1[k] * w1[k * 16 + c];
    t2[c] = fmaxf(a, 0.f);
  }
#pragma unroll
  for (int c = 0; c < 16; c++) {
    float a = 0.f;
#pragma unroll
    for (int k = 0; k < 16; k++) a += t2[k] * w2[k * 16 + c];
    t1[c] = fmaxf(a, 0.f);
  }
  float pf[16];
#pragma unroll
  for (int c = 0; c < 16; c++) {
    float a = 0.f;
#pragma unroll
    for (int k = 0; k < 16; k++) a += t1[k] * w3[k * 16 + c];
    pf[c] = p[c] + a;
  }
  long po = ((long)i * 768 + j) * 16;
  float4 s0 = {pf[0], pf[1], pf[2], pf[3]};
  float4 s1 = {pf[4], pf[5], pf[6], pf[7]};
  float4 s2 = {pf[8], pf[9], pf[10], pf[11]};
  float4 s3 = {pf[12], pf[13], pf[14], pf[15]};
  *(float4*)&pair_out[po] = s0;
  *(float4*)&pair_out[po + 4] = s1;
  *(float4*)&pair_out[po + 8] = s2;
  *(float4*)&pair_out[po + 12] = s3;
  int lo = (i & ~31) - 48;
  int jw = j - lo;
  if ((unsigned)jw < 128u) {
    float m = 0.f;
#pragma unroll
    for (int c = 0; c < 16; c++) m += pf[c];
    m *= (1.f / 16.f);
    float vv = 0.f;
#pragma unroll
    for (int c = 0; c < 16; c++) { float d = pf[c] - m; vv += d * d; }
    float rs = rsqrtf(vv * (1.f / 16.f) + 1e-5f);
    long no = ((long)i * 128 + jw) * 16;
    float4 n0 = {(pf[0] - m) * rs, (pf[1] - m) * rs, (pf[2] - m) * rs, (pf[3] - m) * rs};
    float4 n1 = {(pf[4] - m) * rs, (pf[5] - m) * rs, (pf[6] - m) * rs, (pf[7] - m) * rs};
    float4 n2 = {(pf[8] - m) * rs, (pf[9] - m) * rs, (pf[10] - m) * rs, (pf[11] - m) * rs};
    float4 n3 = {(pf[12] - m) * rs, (pf[13] - m) * rs, (pf[14] - m) * rs, (pf[15] - m) * rs};
    *(float4*)&pnrm[no] = n0;
    *(float4*)&pnrm[no + 4] = n1;
    *(float4*)&pnrm[no + 8] = n2;
    *(float4*)&pnrm[no + 12] = n3;
  }
}

// ---------------------------------------------------------------------------
// K3b: biasA[b][qb][h][qi][kj] = pnrm@(g.Wb) + const  (out-of-range -> -1e30)
// grid 72 (b*24+qb), block 256
__global__ __launch_bounds__(256) void k_bias(
    const float* __restrict__ pnrm, const float* __restrict__ lnp_g,
    const float* __restrict__ lnp_b, const float* __restrict__ Wb,
    float* __restrict__ biasA) {
  int blk = blockIdx.x;
  int b = blk / 24, qb = blk % 24, t = threadIdx.x;
  __shared__ float Wgb[64];
  __shared__ float Kb[4];
  if (t < 64) Wgb[t] = lnp_g[b * 16 + (t >> 2)] * Wb[b * 64 + t];
  if (t < 4) {
    float sK = 0.f;
#pragma unroll
    for (int c = 0; c < 16; c++) sK += lnp_b[b * 16 + c] * Wb[b * 64 + c * 4 + t];
    Kb[t] = sK;
  }
  __syncthreads();
  int kj = t & 127, qh = t >> 7;
  int lo = qb * 32 - 48;
  int j = lo + kj;
  bool valid = (j >= 0 && j < 768);
  for (int qq = 0; qq < 16; qq++) {
    int qi = qh * 16 + qq;
    int i = qb * 32 + qi;
    float o0, o1, o2, o3;
    if (valid) {
      const float4* pv = (const float4*)&pnrm[((long)i * 128 + kj) * 16];
      float4 a = pv[0], b4 = pv[1], c4 = pv[2], d4 = pv[3];
      float nv[16] = {a.x, a.y, a.z, a.w, b4.x, b4.y, b4.z, b4.w,
                      c4.x, c4.y, c4.z, c4.w, d4.x, d4.y, d4.z, d4.w};
      o0 = Kb[0]; o1 = Kb[1]; o2 = Kb[2]; o3 = Kb[3];
#pragma unroll
      for (int c = 0; c < 16; c++) {
        float nvv = nv[c];
        o0 += nvv * Wgb[c * 4 + 0]; o1 += nvv * Wgb[c * 4 + 1];
        o2 += nvv * Wgb[c * 4 + 2]; o3 += nvv * Wgb[c * 4 + 3];
      }
    } else { o0 = o1 = o2 = o3 = -1e30f; }
    long base = (long)(b * 24 + qb) * 4 * 4096 + (long)qi * 128 + kj;
    biasA[base] = o0;
    biasA[base + 4096] = o1;
    biasA[base + 2 * 4096] = o2;
    biasA[base + 3 * 4096] = o3;
  }
}

// ---------------------------------------------------------------------------
// K4: a = LN(x); qkvg = a @ [Wq|Wk|Wv|Wg]  -> [768,512]
// grid 96 (8 rows each), block 256
__global__ __launch_bounds__(256) void k_lnqkvg(
    const float* __restrict__ x, const float* __restrict__ lng,
    const float* __restrict__ lnb, const float* __restrict__ Wq,
    const float* __restrict__ Wk, const float* __restrict__ Wv,
    const float* __restrict__ Wg, float* __restrict__ qkvg) {
  __shared__ float as[8][132];
  int t = threadIdx.x, rr = t >> 5, lane = t & 31;
  int row = blockIdx.x * 8 + rr;
  float4 xv = *(const float4*)&x[row * 128 + lane * 4];
  float ps = xv.x + xv.y + xv.z + xv.w;
  float pq = xv.x * xv.x + xv.y * xv.y + xv.z * xv.z + xv.w * xv.w;
#pragma unroll
  for (int o = 1; o < 32; o <<= 1) { ps += __shfl_xor(ps, o); pq += __shfl_xor(pq, o); }
  float m = ps * (1.f / 128.f);
  float rstd = rsqrtf(pq * (1.f / 128.f) - m * m + 1e-5f);
  float4 gg = *(const float4*)&lng[lane * 4];
  float4 bb = *(const float4*)&lnb[lane * 4];
  float4 av;
  av.x = (xv.x - m) * rstd * gg.x + bb.x;
  av.y = (xv.y - m) * rstd * gg.y + bb.y;
  av.z = (xv.z - m) * rstd * gg.z + bb.z;
  av.w = (xv.w - m) * rstd * gg.w + bb.w;
  *(float4*)&as[rr][lane * 4] = av;
  __syncthreads();
  const float* WA = (t < 128) ? Wq : Wk;
  const float* WB = (t < 128) ? Wv : Wg;
  int cc = t & 127;
  int o1 = (t < 128) ? 0 : 128;
  int o2 = (t < 128) ? 256 : 384;
  float acc0[8] = {0, 0, 0, 0, 0, 0, 0, 0};
  float acc1[8] = {0, 0, 0, 0, 0, 0, 0, 0};
#pragma unroll 4
  for (int k = 0; k < 128; k++) {
    float wa = WA[k * 128 + cc], wb = WB[k * 128 + cc];
#pragma unroll
    for (int q = 0; q < 8; q++) {
      float a = as[q][k];
      acc0[q] += a * wa; acc1[q] += a * wb;
    }
  }
  int rbase = blockIdx.x * 8;
#pragma unroll
  for (int q = 0; q < 8; q++) {
    qkvg[(rbase + q) * 512 + o1 + cc] = acc0[q];
    qkvg[(rbase + q) * 512 + o2 + cc] = acc1[q];
  }
}

// ---------------------------------------------------------------------------
// K5: windowed attention for one (qblock, head); og = (attn@V)*sigmoid(g)
// grid 96 (qb*4+h), block 256
__global__ __launch_bounds__(256) void k_attn(
    const float* __restrict__ qkvg, const float* __restrict__ biasb,
    float* __restrict__ og) {
  int qb = blockIdx.x >> 2, h = blockIdx.x & 3, t = threadIdx.x;
  int i0 = qb * 32, lo = i0 - 48;
  __shared__ float qT[32][33];
  __shared__ float ks[128][36];
  __shared__ float vs[128][36];
  __shared__ float L[32][132];
#pragma unroll
  for (int m = 0; m < 16; m++) {
    int idx = t + 256 * m;
    L[idx >> 7][idx & 127] = biasb[(qb * 4 + h) * 4096 + idx];
  }
#pragma unroll
  for (int m = 0; m < 4; m++) {
    int d = (t >> 5) + 8 * m;
    qT[d][t & 31] = qkvg[(i0 + (t & 31)) * 512 + h * 32 + d];
  }
  {
    int kj = t >> 1, dh = (t & 1) * 16;
    int j = lo + kj;
    if (j >= 0 && j < 768) {
      const float4* sk = (const float4*)&qkvg[j * 512 + 128 + h * 32 + dh];
      const float4* sv = (const float4*)&qkvg[j * 512 + 256 + h * 32 + dh];
#pragma unroll
      for (int m = 0; m < 4; m++) {
        *(float4*)&ks[kj][dh + 4 * m] = sk[m];
        *(float4*)&vs[kj][dh + 4 * m] = sv[m];
      }
    } else {
      float4 zz = {0, 0, 0, 0};
#pragma unroll
      for (int m = 0; m < 4; m++) {
        *(float4*)&ks[kj][dh + 4 * m] = zz;
        *(float4*)&vs[kj][dh + 4 * m] = zz;
      }
    }
  }
  __syncthreads();
  const float scale = 0.17677669529663687f;
  {
    int qi = t & 31, kb = t >> 5;
#pragma unroll 2
    for (int kk = 0; kk < 16; kk++) {
      int kj = kb + 8 * kk;
      float acc = 0.f;
#pragma unroll
      for (int d = 0; d < 32; d++) acc += qT[d][qi] * ks[kj][d];
      L[qi][kj] += acc * scale;
    }
  }
  __syncthreads();
  int qi = t >> 3, sg = t & 7;
  float mx = -1e30f;
#pragma unroll
  for (int k2 = 0; k2 < 16; k2++) mx = fmaxf(mx, L[qi][sg * 16 + k2]);
#pragma unroll
  for (int o = 1; o < 8; o <<= 1) mx = fmaxf(mx, __shfl_xor(mx, o));
  float sum = 0.f;
#pragma unroll
  for (int k2 = 0; k2 < 16; k2++) {
    int kj = sg * 16 + k2;
    float e = __expf(L[qi][kj] - mx);
    L[qi][kj] = e;
    sum += e;
  }
#pragma unroll
  for (int o = 1; o < 8; o <<= 1) sum += __shfl_xor(sum, o);
  float rden = 1.f / sum;
  __syncthreads();
  int d0 = (t & 7) * 4;
  float4 acc = {0, 0, 0, 0};
#pragma unroll 4
  for (int kj = 0; kj < 128; kj++) {
    float p = L[qi][kj];
    float4 v = *(const float4*)&vs[kj][d0];
    acc.x += p * v.x; acc.y += p * v.y; acc.z += p * v.z; acc.w += p * v.w;
  }
  int i = i0 + qi;
  float4 gr = *(const float4*)&qkvg[i * 512 + 384 + h * 32 + d0];
  float4 o4;
  o4.x = acc.x * rden * sigmoidf_(gr.x);
  o4.y = acc.y * rden * sigmoidf_(gr.y);
  o4.z = acc.z * rden * sigmoidf_(gr.z);
  o4.w = acc.w * rden * sigmoidf_(gr.w);
  *(float4*)&og[i * 128 + h * 32 + d0] = o4;
}

// ---------------------------------------------------------------------------
// K6: x += og @ Wo   grid 48 (16 rows), block 256
__global__ __launch_bounds__(256) void k_out(
    const float* __restrict__ og, const float* __restrict__ Wo, float* __restrict__ x) {
  __shared__ float os[16][132];
  int t = threadIdx.x, r0 = blockIdx.x * 16;
#pragma unroll
  for (int m = 0; m < 2; m++) {
    int idx = (t + 256 * m) * 4;
    int rr = idx >> 7, kk = idx & 127;
    *(float4*)&os[rr][kk] = *(const float4*)&og[(r0 + rr) * 128 + kk];
  }
  __syncthreads();
  int c = t & 127, rh = t >> 7;
  float acc[8] = {0, 0, 0, 0, 0, 0, 0, 0};
#pragma unroll 4
  for (int k = 0; k < 128; k++) {
    float w = Wo[k * 128 + c];
#pragma unroll
    for (int rr = 0; rr < 8; rr++) acc[rr] += os[rh * 8 + rr][k] * w;
  }
#pragma unroll
  for (int rr = 0; rr < 8; rr++) x[(r0 + rh * 8 + rr) * 128 + c] += acc[rr];
}

// ---------------------------------------------------------------------------
// K7a: t=LN(x); h = relu(t@Wt1)  [768,512]   grid 96 (8 rows), block 256
__global__ __launch_bounds__(256) void k_tr1(
    const float* __restrict__ x, const float* __restrict__ lng,
    const float* __restrict__ lnb, const float* __restrict__ Wt1,
    float* __restrict__ hbuf) {
  __shared__ float as[8][132];
  int t = threadIdx.x, rr = t >> 5, lane = t & 31;
  int row = blockIdx.x * 8 + rr;
  float4 xv = *(const float4*)&x[row * 128 + lane * 4];
  float ps = xv.x + xv.y + xv.z + xv.w;
  float pq = xv.x * xv.x + xv.y * xv.y + xv.z * xv.z + xv.w * xv.w;
#pragma unroll
  for (int o = 1; o < 32; o <<= 1) { ps += __shfl_xor(ps, o); pq += __shfl_xor(pq, o); }
  float m = ps * (1.f / 128.f);
  float rstd = rsqrtf(pq * (1.f / 128.f) - m * m + 1e-5f);
  float4 gg = *(const float4*)&lng[lane * 4];
  float4 bb = *(const float4*)&lnb[lane * 4];
  float4 av;
  av.x = (xv.x - m) * rstd * gg.x + bb.x;
  av.y = (xv.y - m) * rstd * gg.y + bb.y;
  av.z = (xv.z - m) * rstd * gg.z + bb.z;
  av.w = (xv.w - m) * rstd * gg.w + bb.w;
  *(float4*)&as[rr][lane * 4] = av;
  __syncthreads();
  float acc0[8] = {0, 0, 0, 0, 0, 0, 0, 0};
  float acc1[8] = {0, 0, 0, 0, 0, 0, 0, 0};
#pragma unroll 4
  for (int k = 0; k < 128; k++) {
    float w0 = Wt1[k * 512 + t], w1 = Wt1[k * 512 + 256 + t];
#pragma unroll
    for (int q = 0; q < 8; q++) {
      float a = as[q][k];
      acc0[q] += a * w0; acc1[q] += a * w1;
    }
  }
  int rbase = blockIdx.x * 8;
#pragma unroll
  for (int q = 0; q < 8; q++) {
    hbuf[(rbase + q) * 512 + t] = fmaxf(acc0[q], 0.f);
    hbuf[(rbase + q) * 512 + 256 + t] = fmaxf(acc1[q], 0.f);
  }
}

// ---------------------------------------------------------------------------
// K7b: x += h @ Wt2   grid 96 (8 rows), block 256
__global__ __launch_bounds__(256) void k_tr2(
    const float* __restrict__ hbuf, const float* __restrict__ Wt2, float* __restrict__ x) {
  __shared__ float hs[8][516];
  int t = threadIdx.x, r0 = blockIdx.x * 8;
#pragma unroll
  for (int m = 0; m < 4; m++) {
    int idx = (t + 256 * m) * 4;
    int rr = idx >> 9, kk = idx & 511;
    *(float4*)&hs[rr][kk] = *(const float4*)&hbuf[(r0 + rr) * 512 + kk];
  }
  __syncthreads();
  int c = t & 127, rh = t >> 7;
  float acc[4] = {0, 0, 0, 0};
#pragma unroll 4
  for (int k = 0; k < 512; k++) {
    float w = Wt2[k * 128 + c];
#pragma unroll
    for (int rr = 0; rr < 4; rr++) acc[rr] += hs[rh * 4 + rr][k] * w;
  }
#pragma unroll
  for (int rr = 0; rr < 4; rr++) x[(r0 + rh * 4 + rr) * 128 + c] += acc[rr];
}

// ---------------------------------------------------------------------------
// K8: qout = relu(x@W_proj); a_out = mean over 3 atoms  grid 256, block 384
__global__ __launch_bounds__(384) void k_final(
    const float* __restrict__ x, const float* __restrict__ W_proj,
    float* __restrict__ out) {
  __shared__ float xs[384];
  int tk = blockIdx.x, t = threadIdx.x;
  xs[t] = x[tk * 384 + t];
  __syncthreads();
  float a0 = 0, a1 = 0, a2 = 0;
#pragma unroll 4
  for (int k = 0; k < 128; k++) {
    float w = W_proj[k * 384 + t];
    a0 += xs[k] * w; a1 += xs[128 + k] * w; a2 += xs[256 + k] * w;
  }
  a0 = fmaxf(a0, 0.f); a1 = fmaxf(a1, 0.f); a2 = fmaxf(a2, 0.f);
  out[98304 + (tk * 3 + 0) * 384 + t] = a0;
  out[98304 + (tk * 3 + 1) * 384 + t] = a1;
  out[98304 + (tk * 3 + 2) * 384 + t] = a2;
  out[tk * 384 + t] = (a0 + a1 + a2) * (1.f / 3.f);
}

// ---------------------------------------------------------------------------
extern "C" void kernel_launch(void* const* d_in, const int* in_sizes, int n_in,
                              void* d_out, int out_size, void* d_ws, size_t ws_size,
                              hipStream_t stream) {
  const float* ref_pos  = (const float*)d_in[0];
  const int*   uid      = (const int*)d_in[1];
  const float* r        = (const float*)d_in[2];
  const float* s        = (const float*)d_in[3];
  const float* z        = (const float*)d_in[4];
  const float* W_pos    = (const float*)d_in[5];
  const float* Wpo      = (const float*)d_in[6];
  const float* Wisd     = (const float*)d_in[7];
  const float* Wmask    = (const float*)d_in[8];
  const float* Wca      = (const float*)d_in[9];
  const float* Wcb      = (const float*)d_in[10];
  const float* ln_s_g   = (const float*)d_in[11];
  const float* ln_s_b   = (const float*)d_in[12];
  const float* W_single = (const float*)d_in[13];
  const float* ln_z_g   = (const float*)d_in[14];
  const float* ln_z_b   = (const float*)d_in[15];
  const float* W_pair   = (const float*)d_in[16];
  const float* W_noisy  = (const float*)d_in[17];
  const float* W_mlp1   = (const float*)d_in[18];
  const float* W_mlp2   = (const float*)d_in[19];
  const float* W_mlp3   = (const float*)d_in[20];
  const float* at_ln_g  = (const float*)d_in[21];
  const float* at_ln_b  = (const float*)d_in[22];
  const float* at_Wq    = (const float*)d_in[23];
  const float* at_Wk    = (const float*)d_in[24];
  const float* at_Wv    = (const float*)d_in[25];
  const float* at_Wg    = (const float*)d_in[26];
  const float* at_lnp_g = (const float*)d_in[27];
  const float* at_lnp_b = (const float*)d_in[28];
  const float* at_Wb    = (const float*)d_in[29];
  const float* at_Wo    = (const float*)d_in[30];
  const float* at_ln2_g = (const float*)d_in[31];
  const float* at_ln2_b = (const float*)d_in[32];
  const float* at_Wt1   = (const float*)d_in[33];
  const float* at_Wt2   = (const float*)d_in[34];
  const float* W_proj   = (const float*)d_in[35];
  float* out = (float*)d_out;
  float* W = (float*)d_ws;
  float* x     = W;                 //   98304
  float* ca    = W + 98304;         //   12288
  float* cb    = W + 110592;        //   12288
  float* zp    = W + 122880;        // 1048576
  float* pnrm  = W + 1171456;       // 1572864
  float* biasA = W + 2744320;       // 1179648
  float* qkvg  = W + 3923968;       //  393216
  float* og    = W + 4317184;       //   98304
  float* hbuf  = W + 4415488;       //  393216  (total 4808704 f = 19.2 MB)

  k_prep<<<768, 256, 0, stream>>>(ref_pos, r, s, W_pos, W_noisy, ln_s_g, ln_s_b,
                                  W_single, Wca, Wcb, out + 393216, x, ca, cb);
  k_zp<<<4096, 256, 0, stream>>>(z, ln_z_g, ln_z_b, W_pair, zp);
  k_pair<<<2304, 256, 0, stream>>>(ref_pos, uid, Wpo, Wisd, Wmask, W_mlp1, W_mlp2,
                                   W_mlp3, zp, ca, cb, out + 491520, pnrm);
  k_bias<<<72, 256, 0, stream>>>(pnrm, at_lnp_g, at_lnp_b, at_Wb, biasA);
  for (int b = 0; b < 3; b++) {
    k_lnqkvg<<<96, 256, 0, stream>>>(x, at_ln_g + b * 128, at_ln_b + b * 128,
                                     at_Wq + b * 16384, at_Wk + b * 16384,
                                     at_Wv + b * 16384, at_Wg + b * 16384, qkvg);
    k_attn<<<96, 256, 0, stream>>>(qkvg, biasA + b * 393216, og);
    k_out<<<48, 256, 0, stream>>>(og, at_Wo + b * 16384, x);
    k_tr1<<<96, 256, 0, stream>>>(x, at_ln2_g + b * 128, at_ln2_b + b * 128,
                                  at_Wt1 + b * 65536, hbuf);
    k_tr2<<<96, 256, 0, stream>>>(hbuf, at_Wt2 + b * 65536, x);
  }
  k_final<<<256, 384, 0, stream>>>(x, W_proj, out);
}

// Round 2
// 341.207 us; speedup vs baseline: 1.2799x; 1.2799x over previous
//
#include <hip/hip_runtime.h>
#include <math.h>

// N=768 atoms, T=256 tokens, CA=128, CP=16, CZ=128, CS=384, CT=384, H=4, DH=32
// d_out: a_out[256*384]@0, qout[768*384]@98304, c[768*128]@393216, pair[768*768*16]@491520

__device__ __forceinline__ float sigmoidf_(float v) { return 1.f / (1.f + __expf(-v)); }

// ---------------------------------------------------------------------------
// k_tok: SLN = LN(s[tok]); ct[tok,c] = SLN @ W_single   grid 256, block 128
__global__ __launch_bounds__(128) void k_tok(
    const float* __restrict__ s, const float* __restrict__ g,
    const float* __restrict__ b, const float* __restrict__ W_single,
    float* __restrict__ ct) {
  int tok = blockIdx.x, t = threadIdx.x;
  __shared__ float sln[384];
  __shared__ float ws[48 * 128];
  __shared__ float red[4];
  float v0 = s[tok * 384 + t], v1 = s[tok * 384 + 128 + t], v2 = s[tok * 384 + 256 + t];
  float ps = v0 + v1 + v2, pq = v0 * v0 + v1 * v1 + v2 * v2;
#pragma unroll
  for (int o = 1; o < 64; o <<= 1) { ps += __shfl_xor(ps, o); pq += __shfl_xor(pq, o); }
  if ((t & 63) == 0) { red[t >> 6] = ps; red[2 + (t >> 6)] = pq; }
  __syncthreads();
  float mean = (red[0] + red[1]) * (1.f / 384.f);
  float var = (red[2] + red[3]) * (1.f / 384.f) - mean * mean;
  float rstd = rsqrtf(var + 1e-5f);
  sln[t] = (v0 - mean) * rstd * g[t] + b[t];
  sln[128 + t] = (v1 - mean) * rstd * g[128 + t] + b[128 + t];
  sln[256 + t] = (v2 - mean) * rstd * g[256 + t] + b[256 + t];
  float acc = 0.f;
  for (int c0 = 0; c0 < 384; c0 += 48) {
    __syncthreads();
#pragma unroll
    for (int m = 0; m < 12; m++) {
      int idx = (t + 128 * m) * 4;
      *(float4*)&ws[idx] = *(const float4*)&W_single[c0 * 128 + idx];
    }
    __syncthreads();
#pragma unroll 8
    for (int kk = 0; kk < 48; kk++) acc += sln[c0 + kk] * ws[kk * 128 + t];
  }
  ct[tok * 128 + t] = acc;
}

// ---------------------------------------------------------------------------
// k_atoms: c = c0 + ct[tok]; x = c0 + r@W_noisy; ca/cb = relu(c)@Wca/Wcb
// grid 768, block 128
__global__ __launch_bounds__(128) void k_atoms(
    const float* __restrict__ ref_pos, const float* __restrict__ r,
    const float* __restrict__ ct, const float* __restrict__ W_pos,
    const float* __restrict__ W_noisy, const float* __restrict__ Wca,
    const float* __restrict__ Wcb, float* __restrict__ c_out,
    float* __restrict__ x, float* __restrict__ ca, float* __restrict__ cb) {
  int i = blockIdx.x, t = threadIdx.x;
  __shared__ float rc[128];
  float p0 = ref_pos[i * 3], p1 = ref_pos[i * 3 + 1], p2 = ref_pos[i * 3 + 2];
  float r0 = r[i * 3], r1 = r[i * 3 + 1], r2 = r[i * 3 + 2];
  float c0 = p0 * W_pos[t] + p1 * W_pos[128 + t] + p2 * W_pos[256 + t];
  x[i * 128 + t] = c0 + r0 * W_noisy[t] + r1 * W_noisy[128 + t] + r2 * W_noisy[256 + t];
  float cc = c0 + ct[(i & 255) * 128 + t];
  c_out[i * 128 + t] = cc;
  rc[t] = fmaxf(cc, 0.f);
  __syncthreads();
  int out_id = t >> 2, q = t & 3;
  const float* Wm = (out_id < 16) ? Wca : Wcb;
  int ch = out_id & 15;
  float acc = 0.f;
#pragma unroll
  for (int kk = 0; kk < 32; kk++) { int k = q * 32 + kk; acc += rc[k] * Wm[k * 16 + ch]; }
  acc += __shfl_xor(acc, 1);
  acc += __shfl_xor(acc, 2);
  if (q == 0) { if (out_id < 16) ca[i * 16 + ch] = acc; else cb[i * 16 + ch] = acc; }
}

// ---------------------------------------------------------------------------
// k_zp: zp[65536,16] = LN(z)@W_pair   grid 4096, block 256
__global__ __launch_bounds__(256) void k_zp(
    const float* __restrict__ z, const float* __restrict__ g,
    const float* __restrict__ lb, const float* __restrict__ W_pair,
    float* __restrict__ zp) {
  __shared__ float wT[16][132];
  __shared__ float zs[16][132];
  __shared__ float sWg[16], Bc[16];
  int t = threadIdx.x;
#pragma unroll
  for (int m = 0; m < 8; m++) {
    int e = t + 256 * m;
    int row = e >> 4, ch = e & 15;
    wT[ch][row] = g[row] * W_pair[e];
  }
  __syncthreads();
  if (t < 32) {
    int ch = t & 15;
    float a = 0.f;
    if (t < 16) {
#pragma unroll 8
      for (int k = 0; k < 128; k++) a += wT[ch][k];
      sWg[ch] = a;
    } else {
#pragma unroll 8
      for (int k = 0; k < 128; k++) a += lb[k] * W_pair[k * 16 + ch];
      Bc[ch] = a;
    }
  }
  int row = t >> 4, kk = (t & 15) * 8;
  long base = ((long)blockIdx.x * 16 + row) * 128 + kk;
  float4 a4 = *(const float4*)&z[base];
  float4 b4 = *(const float4*)&z[base + 4];
  *(float4*)&zs[row][kk] = a4;
  *(float4*)&zs[row][kk + 4] = b4;
  float ps = a4.x + a4.y + a4.z + a4.w + b4.x + b4.y + b4.z + b4.w;
  float pq = a4.x * a4.x + a4.y * a4.y + a4.z * a4.z + a4.w * a4.w +
             b4.x * b4.x + b4.y * b4.y + b4.z * b4.z + b4.w * b4.w;
#pragma unroll
  for (int o = 1; o < 16; o <<= 1) { ps += __shfl_xor(ps, o); pq += __shfl_xor(pq, o); }
  float m = ps * (1.f / 128.f);
  float rstd = rsqrtf(pq * (1.f / 128.f) - m * m + 1e-5f);
  __syncthreads();
  int ch = t & 15;
  float dotv = 0.f;
#pragma unroll 8
  for (int k4 = 0; k4 < 32; k4++) {
    float4 zv = *(float4*)&zs[row][k4 * 4];
    float4 wv = *(float4*)&wT[ch][k4 * 4];
    dotv += zv.x * wv.x + zv.y * wv.y + zv.z * wv.z + zv.w * wv.w;
  }
  zp[((long)blockIdx.x * 16 + row) * 16 + ch] = rstd * (dotv - m * sWg[ch]) + Bc[ch];
}

// ---------------------------------------------------------------------------
// k_pair: pair + MLP + window LN16 -> pnrm.  Weights via wave-uniform loads.
// grid 2304 (i*3+jb), block 256
__global__ __launch_bounds__(256) void k_pair(
    const float* __restrict__ ref_pos, const int* __restrict__ uid,
    const float* __restrict__ Wpo, const float* __restrict__ Wisd,
    const float* __restrict__ Wmask, const float* __restrict__ W1,
    const float* __restrict__ W2, const float* __restrict__ W3,
    const float* __restrict__ zp, const float* __restrict__ ca,
    const float* __restrict__ cb, float* __restrict__ pair_out,
    float* __restrict__ pnrm) {
  int i = blockIdx.x / 3, jb = blockIdx.x % 3, t = threadIdx.x;
  int j = jb * 256 + t;
  float d0 = ref_pos[i * 3] - ref_pos[j * 3];
  float d1 = ref_pos[i * 3 + 1] - ref_pos[j * 3 + 1];
  float d2 = ref_pos[i * 3 + 2] - ref_pos[j * 3 + 2];
  float mask = (uid[i] == uid[j]) ? 1.f : 0.f;
  float inv = 1.f / (1.f + d0 * d0 + d1 * d1 + d2 * d2);
  float zb[16];
  {
    const float4* zpv = (const float4*)&zp[(((i & 255) << 8) + t) * 16];
    const float4* cbv = (const float4*)&cb[j * 16];
    float4 q0 = zpv[0], q1 = zpv[1], q2 = zpv[2], q3 = zpv[3];
    float4 b0 = cbv[0], b1 = cbv[1], b2 = cbv[2], b3 = cbv[3];
    zb[0] = q0.x + b0.x; zb[1] = q0.y + b0.y; zb[2] = q0.z + b0.z; zb[3] = q0.w + b0.w;
    zb[4] = q1.x + b1.x; zb[5] = q1.y + b1.y; zb[6] = q1.z + b1.z; zb[7] = q1.w + b1.w;
    zb[8] = q2.x + b2.x; zb[9] = q2.y + b2.y; zb[10] = q2.z + b2.z; zb[11] = q2.w + b2.w;
    zb[12] = q3.x + b3.x; zb[13] = q3.y + b3.y; zb[14] = q3.z + b3.z; zb[15] = q3.w + b3.w;
  }
  float p[16];
#pragma unroll
  for (int c = 0; c < 16; c++)
    p[c] = mask * (d0 * Wpo[c] + d1 * Wpo[16 + c] + d2 * Wpo[32 + c] + inv * Wisd[c] + Wmask[c])
           + zb[c] + ca[i * 16 + c];
  float t1[16], t2[16];
#pragma unroll
  for (int c = 0; c < 16; c++) t1[c] = fmaxf(p[c], 0.f);
#pragma unroll
  for (int c = 0; c < 16; c++) {
    float a = 0.f;
#pragma unroll
    for (int k = 0; k < 16; k++) a += t1[k] * W1[k * 16 + c];
    t2[c] = fmaxf(a, 0.f);
  }
#pragma unroll
  for (int c = 0; c < 16; c++) {
    float a = 0.f;
#pragma unroll
    for (int k = 0; k < 16; k++) a += t2[k] * W2[k * 16 + c];
    t1[c] = fmaxf(a, 0.f);
  }
  float pf[16];
#pragma unroll
  for (int c = 0; c < 16; c++) {
    float a = 0.f;
#pragma unroll
    for (int k = 0; k < 16; k++) a += t1[k] * W3[k * 16 + c];
    pf[c] = p[c] + a;
  }
  long po = ((long)i * 768 + j) * 16;
  float4 s0 = {pf[0], pf[1], pf[2], pf[3]};
  float4 s1 = {pf[4], pf[5], pf[6], pf[7]};
  float4 s2 = {pf[8], pf[9], pf[10], pf[11]};
  float4 s3 = {pf[12], pf[13], pf[14], pf[15]};
  *(float4*)&pair_out[po] = s0;
  *(float4*)&pair_out[po + 4] = s1;
  *(float4*)&pair_out[po + 8] = s2;
  *(float4*)&pair_out[po + 12] = s3;
  int lo = (i & ~31) - 48;
  int jw = j - lo;
  if ((unsigned)jw < 128u) {
    float m = 0.f;
#pragma unroll
    for (int c = 0; c < 16; c++) m += pf[c];
    m *= (1.f / 16.f);
    float vv = 0.f;
#pragma unroll
    for (int c = 0; c < 16; c++) { float d = pf[c] - m; vv += d * d; }
    float rs = rsqrtf(vv * (1.f / 16.f) + 1e-5f);
    long no = ((long)i * 128 + jw) * 16;
    float4 n0 = {(pf[0] - m) * rs, (pf[1] - m) * rs, (pf[2] - m) * rs, (pf[3] - m) * rs};
    float4 n1 = {(pf[4] - m) * rs, (pf[5] - m) * rs, (pf[6] - m) * rs, (pf[7] - m) * rs};
    float4 n2 = {(pf[8] - m) * rs, (pf[9] - m) * rs, (pf[10] - m) * rs, (pf[11] - m) * rs};
    float4 n3 = {(pf[12] - m) * rs, (pf[13] - m) * rs, (pf[14] - m) * rs, (pf[15] - m) * rs};
    *(float4*)&pnrm[no] = n0;
    *(float4*)&pnrm[no + 4] = n1;
    *(float4*)&pnrm[no + 8] = n2;
    *(float4*)&pnrm[no + 12] = n3;
  }
}

// ---------------------------------------------------------------------------
// k_bias: all 3 layers, all 4 heads at once.  grid 768 (qb*32+qi), block 128 (kj)
__global__ __launch_bounds__(128) void k_bias(
    const float* __restrict__ pnrm, const float* __restrict__ lnp_g,
    const float* __restrict__ lnp_b, const float* __restrict__ Wb,
    float* __restrict__ biasA) {
  int qb = blockIdx.x >> 5, qi = blockIdx.x & 31, t = threadIdx.x;
  __shared__ float Wgb[3][64];
  __shared__ float Kb[3][4];
  if (t < 64) {
    int c = t >> 2;
#pragma unroll
    for (int bq = 0; bq < 3; bq++) Wgb[bq][t] = lnp_g[bq * 16 + c] * Wb[bq * 64 + t];
  } else if (t < 76) {
    int bq = (t - 64) >> 2, hh = (t - 64) & 3;
    float a = 0.f;
#pragma unroll
    for (int c = 0; c < 16; c++) a += lnp_b[bq * 16 + c] * Wb[bq * 64 + c * 4 + hh];
    Kb[bq][hh] = a;
  }
  __syncthreads();
  int i = qb * 32 + qi;
  int kj = t;
  int j = qb * 32 - 48 + kj;
  bool valid = (j >= 0 && j < 768);
  float nv[16];
  if (valid) {
    const float4* pv = (const float4*)&pnrm[((long)i * 128 + kj) * 16];
    float4 a = pv[0], b4 = pv[1], c4 = pv[2], d4 = pv[3];
    nv[0] = a.x; nv[1] = a.y; nv[2] = a.z; nv[3] = a.w;
    nv[4] = b4.x; nv[5] = b4.y; nv[6] = b4.z; nv[7] = b4.w;
    nv[8] = c4.x; nv[9] = c4.y; nv[10] = c4.z; nv[11] = c4.w;
    nv[12] = d4.x; nv[13] = d4.y; nv[14] = d4.z; nv[15] = d4.w;
  }
#pragma unroll
  for (int bq = 0; bq < 3; bq++) {
    float o0, o1, o2, o3;
    if (valid) {
      o0 = Kb[bq][0]; o1 = Kb[bq][1]; o2 = Kb[bq][2]; o3 = Kb[bq][3];
#pragma unroll
      for (int c = 0; c < 16; c++) {
        float nvv = nv[c];
        o0 += nvv * Wgb[bq][c * 4 + 0]; o1 += nvv * Wgb[bq][c * 4 + 1];
        o2 += nvv * Wgb[bq][c * 4 + 2]; o3 += nvv * Wgb[bq][c * 4 + 3];
      }
    } else { o0 = o1 = o2 = o3 = -1e30f; }
    long base = (long)(bq * 96 + qb * 4) * 4096 + (long)qi * 128 + kj;
    biasA[base] = o0;
    biasA[base + 4096] = o1;
    biasA[base + 2 * 4096] = o2;
    biasA[base + 3 * 4096] = o3;
  }
}

// ---------------------------------------------------------------------------
// k_qkvg: a=LN(x); tile GEMM into qkvg[768,512].  grid 384 (rb*8+bn), block 256
__global__ __launch_bounds__(256) void k_qkvg(
    const float* __restrict__ x, const float* __restrict__ lng,
    const float* __restrict__ lnb, const float* __restrict__ Wq,
    const float* __restrict__ Wk, const float* __restrict__ Wv,
    const float* __restrict__ Wg, float* __restrict__ qkvg) {
  __shared__ float As[128][18];
  __shared__ float Ws[128][66];
  int t = threadIdx.x;
  int rb = blockIdx.x >> 3, bn = blockIdx.x & 7;
  int r0 = rb * 16;
  const float* Wm = (bn < 2) ? Wq : (bn < 4) ? Wk : (bn < 6) ? Wv : Wg;
  int c0 = (bn & 1) * 64;
  int ncol0 = (bn >> 1) * 128 + c0;
#pragma unroll
  for (int m = 0; m < 8; m++) {
    int idx = t + 256 * m;
    int row = idx >> 4, c4 = (idx & 15) * 4;
    *(float4*)&Ws[row][c4] = *(const float4*)&Wm[row * 128 + c0 + c4];
  }
  {
    int rr = t >> 4, tt = t & 15;
    int row = r0 + rr;
    float4 x0 = *(const float4*)&x[row * 128 + tt * 8];
    float4 x1 = *(const float4*)&x[row * 128 + tt * 8 + 4];
    float ps = x0.x + x0.y + x0.z + x0.w + x1.x + x1.y + x1.z + x1.w;
    float pq = x0.x * x0.x + x0.y * x0.y + x0.z * x0.z + x0.w * x0.w +
               x1.x * x1.x + x1.y * x1.y + x1.z * x1.z + x1.w * x1.w;
#pragma unroll
    for (int o = 1; o < 16; o <<= 1) { ps += __shfl_xor(ps, o); pq += __shfl_xor(pq, o); }
    float m = ps * (1.f / 128.f);
    float rstd = rsqrtf(pq * (1.f / 128.f) - m * m + 1e-5f);
    float4 g0 = *(const float4*)&lng[tt * 8], g1 = *(const float4*)&lng[tt * 8 + 4];
    float4 b0 = *(const float4*)&lnb[tt * 8], b1 = *(const float4*)&lnb[tt * 8 + 4];
    As[tt * 8 + 0][rr] = (x0.x - m) * rstd * g0.x + b0.x;
    As[tt * 8 + 1][rr] = (x0.y - m) * rstd * g0.y + b0.y;
    As[tt * 8 + 2][rr] = (x0.z - m) * rstd * g0.z + b0.z;
    As[tt * 8 + 3][rr] = (x0.w - m) * rstd * g0.w + b0.w;
    As[tt * 8 + 4][rr] = (x1.x - m) * rstd * g1.x + b1.x;
    As[tt * 8 + 5][rr] = (x1.y - m) * rstd * g1.y + b1.y;
    As[tt * 8 + 6][rr] = (x1.z - m) * rstd * g1.z + b1.z;
    As[tt * 8 + 7][rr] = (x1.w - m) * rstd * g1.w + b1.w;
  }
  __syncthreads();
  int ty = t >> 5, tx = t & 31;
  float a00 = 0, a01 = 0, a10 = 0, a11 = 0;
#pragma unroll 8
  for (int k = 0; k < 128; k++) {
    float2 a2 = *(float2*)&As[k][ty * 2];
    float2 w2 = *(float2*)&Ws[k][tx * 2];
    a00 += a2.x * w2.x; a01 += a2.x * w2.y;
    a10 += a2.y * w2.x; a11 += a2.y * w2.y;
  }
  int row = r0 + ty * 2;
  float2 o0 = {a00, a01}, o1 = {a10, a11};
  *(float2*)&qkvg[row * 512 + ncol0 + tx * 2] = o0;
  *(float2*)&qkvg[(row + 1) * 512 + ncol0 + tx * 2] = o1;
}

// ---------------------------------------------------------------------------
// k_attn: windowed attention per (qb,h).  grid 96, block 256
__global__ __launch_bounds__(256) void k_attn(
    const float* __restrict__ qkvg, const float* __restrict__ biasb,
    float* __restrict__ og) {
  int qb = blockIdx.x >> 2, h = blockIdx.x & 3, t = threadIdx.x;
  int i0 = qb * 32, lo = i0 - 48;
  __shared__ float qs[32][36];
  __shared__ float ks[128][36];
  __shared__ float vs[128][36];
  __shared__ float L[32][132];
#pragma unroll
  for (int m = 0; m < 4; m++) {
    int idx = t + 256 * m;
    *(float4*)&L[idx >> 5][(idx & 31) * 4] = *(const float4*)&biasb[(qb * 4 + h) * 4096 + idx * 4];
  }
  {
    int qi = t >> 3, dq = (t & 7) * 4;
    *(float4*)&qs[qi][dq] = *(const float4*)&qkvg[(i0 + qi) * 512 + h * 32 + dq];
  }
  {
    int kj = t >> 1, dh = (t & 1) * 16;
    int j = lo + kj;
    if (j >= 0 && j < 768) {
      const float4* sk = (const float4*)&qkvg[j * 512 + 128 + h * 32 + dh];
      const float4* sv = (const float4*)&qkvg[j * 512 + 256 + h * 32 + dh];
#pragma unroll
      for (int m = 0; m < 4; m++) {
        *(float4*)&ks[kj][dh + 4 * m] = sk[m];
        *(float4*)&vs[kj][dh + 4 * m] = sv[m];
      }
    } else {
      float4 zz = {0, 0, 0, 0};
#pragma unroll
      for (int m = 0; m < 4; m++) {
        *(float4*)&ks[kj][dh + 4 * m] = zz;
        *(float4*)&vs[kj][dh + 4 * m] = zz;
      }
    }
  }
  __syncthreads();
  const float scale = 0.17677669529663687f;
  {
    int qi = t & 31, kb = t >> 5;
    float4 qr[8];
#pragma unroll
    for (int m = 0; m < 8; m++) qr[m] = *(float4*)&qs[qi][m * 4];
#pragma unroll 2
    for (int kk = 0; kk < 16; kk++) {
      int kj = kb * 16 + kk;
      float acc = 0.f;
#pragma unroll
      for (int m = 0; m < 8; m++) {
        float4 kv = *(float4*)&ks[kj][m * 4];
        acc += qr[m].x * kv.x + qr[m].y * kv.y + qr[m].z * kv.z + qr[m].w * kv.w;
      }
      L[qi][kj] += acc * scale;
    }
  }
  __syncthreads();
  int qi = t >> 3, sg = t & 7;
  float mx = -1e30f;
#pragma unroll
  for (int k2 = 0; k2 < 16; k2++) mx = fmaxf(mx, L[qi][sg * 16 + k2]);
#pragma unroll
  for (int o = 1; o < 8; o <<= 1) mx = fmaxf(mx, __shfl_xor(mx, o));
  float sum = 0.f;
#pragma unroll
  for (int k2 = 0; k2 < 16; k2++) {
    int kj = sg * 16 + k2;
    float e = __expf(L[qi][kj] - mx);
    L[qi][kj] = e;
    sum += e;
  }
#pragma unroll
  for (int o = 1; o < 8; o <<= 1) sum += __shfl_xor(sum, o);
  float rden = 1.f / sum;
  __syncthreads();
  int d0 = (t & 7) * 4;
  float4 acc = {0, 0, 0, 0};
#pragma unroll 4
  for (int kj = 0; kj < 128; kj++) {
    float p = L[qi][kj];
    float4 v = *(const float4*)&vs[kj][d0];
    acc.x += p * v.x; acc.y += p * v.y; acc.z += p * v.z; acc.w += p * v.w;
  }
  int i = i0 + qi;
  float4 gr = *(const float4*)&qkvg[i * 512 + 384 + h * 32 + d0];
  float4 o4;
  o4.x = acc.x * rden * sigmoidf_(gr.x);
  o4.y = acc.y * rden * sigmoidf_(gr.y);
  o4.z = acc.z * rden * sigmoidf_(gr.z);
  o4.w = acc.w * rden * sigmoidf_(gr.w);
  *(float4*)&og[i * 128 + h * 32 + d0] = o4;
}

// ---------------------------------------------------------------------------
// k_fused: x += og@Wo; t=LN(x); x += relu(t@Wt1)@Wt2.  grid 96 (8 rows), block 256
__global__ __launch_bounds__(256) void k_fused(
    const float* __restrict__ og, const float* __restrict__ Wo,
    const float* __restrict__ g2, const float* __restrict__ b2,
    const float* __restrict__ Wt1, const float* __restrict__ Wt2,
    float* __restrict__ x) {
  int t = threadIdx.x;
  int r0 = blockIdx.x * 8;
  __shared__ float os[8][132];
  __shared__ float xn[8][132];
  __shared__ float a[8][132];
  __shared__ float h[8][516];
  __shared__ float wc[8192];
  {
    int rr = t >> 5, c4 = (t & 31) * 4;
    *(float4*)&os[rr][c4] = *(const float4*)&og[(r0 + rr) * 128 + c4];
    *(float4*)&xn[rr][c4] = *(const float4*)&x[(r0 + rr) * 128 + c4];
  }
  int c = t & 127, rh = t >> 7;
  float ac[4] = {0, 0, 0, 0};
  for (int k0 = 0; k0 < 128; k0 += 64) {
    __syncthreads();
#pragma unroll
    for (int m = 0; m < 8; m++) {
      int idx = (t + 256 * m) * 4;
      *(float4*)&wc[idx] = *(const float4*)&Wo[k0 * 128 + idx];
    }
    __syncthreads();
#pragma unroll 4
    for (int kk = 0; kk < 64; kk++) {
      float w = wc[kk * 128 + c];
      int k = k0 + kk;
      ac[0] += os[rh * 4 + 0][k] * w; ac[1] += os[rh * 4 + 1][k] * w;
      ac[2] += os[rh * 4 + 2][k] * w; ac[3] += os[rh * 4 + 3][k] * w;
    }
  }
  __syncthreads();
#pragma unroll
  for (int rr = 0; rr < 4; rr++) xn[rh * 4 + rr][c] += ac[rr];
  __syncthreads();
  {
    int rr = t >> 5, tt = t & 31;
    float4 xv = *(float4*)&xn[rr][tt * 4];
    float ps = xv.x + xv.y + xv.z + xv.w;
    float pq = xv.x * xv.x + xv.y * xv.y + xv.z * xv.z + xv.w * xv.w;
#pragma unroll
    for (int o = 1; o < 32; o <<= 1) { ps += __shfl_xor(ps, o); pq += __shfl_xor(pq, o); }
    float m = ps * (1.f / 128.f);
    float rstd = rsqrtf(pq * (1.f / 128.f) - m * m + 1e-5f);
    float4 gg = *(const float4*)&g2[tt * 4];
    float4 bb = *(const float4*)&b2[tt * 4];
    float4 av;
    av.x = (xv.x - m) * rstd * gg.x + bb.x;
    av.y = (xv.y - m) * rstd * gg.y + bb.y;
    av.z = (xv.z - m) * rstd * gg.z + bb.z;
    av.w = (xv.w - m) * rstd * gg.w + bb.w;
    *(float4*)&a[rr][tt * 4] = av;
  }
  int rr3 = t >> 5, cg = t & 31;
  float acc16[16];
#pragma unroll
  for (int e = 0; e < 16; e++) acc16[e] = 0.f;
  for (int k0 = 0; k0 < 128; k0 += 16) {
    __syncthreads();
#pragma unroll
    for (int m = 0; m < 8; m++) {
      int idx = (t + 256 * m) * 4;
      *(float4*)&wc[idx] = *(const float4*)&Wt1[k0 * 512 + idx];
    }
    __syncthreads();
#pragma unroll 2
    for (int kk = 0; kk < 16; kk++) {
      float av = a[rr3][k0 + kk];
#pragma unroll
      for (int q = 0; q < 4; q++) {
        float4 w4 = *(float4*)&wc[kk * 512 + q * 128 + cg * 4];
        acc16[q * 4 + 0] += av * w4.x; acc16[q * 4 + 1] += av * w4.y;
        acc16[q * 4 + 2] += av * w4.z; acc16[q * 4 + 3] += av * w4.w;
      }
    }
  }
  __syncthreads();
#pragma unroll
  for (int q = 0; q < 4; q++) {
    float4 hv = {fmaxf(acc16[q * 4 + 0], 0.f), fmaxf(acc16[q * 4 + 1], 0.f),
                 fmaxf(acc16[q * 4 + 2], 0.f), fmaxf(acc16[q * 4 + 3], 0.f)};
    *(float4*)&h[rr3][q * 128 + cg * 4] = hv;
  }
  float ac2[4] = {0, 0, 0, 0};
  for (int k0 = 0; k0 < 512; k0 += 64) {
    __syncthreads();
#pragma unroll
    for (int m = 0; m < 8; m++) {
      int idx = (t + 256 * m) * 4;
      *(float4*)&wc[idx] = *(const float4*)&Wt2[k0 * 128 + idx];
    }
    __syncthreads();
#pragma unroll 4
    for (int kk = 0; kk < 64; kk++) {
      float w = wc[kk * 128 + c];
      int k = k0 + kk;
      ac2[0] += h[rh * 4 + 0][k] * w; ac2[1] += h[rh * 4 + 1][k] * w;
      ac2[2] += h[rh * 4 + 2][k] * w; ac2[3] += h[rh * 4 + 3][k] * w;
    }
  }
#pragma unroll
  for (int rr = 0; rr < 4; rr++)
    x[(r0 + rh * 4 + rr) * 128 + c] = xn[rh * 4 + rr][c] + ac2[rr];
}

// ---------------------------------------------------------------------------
// k_final: qout = relu(x@W_proj); a_out = mean over 3 atoms  grid 256, block 384
__global__ __launch_bounds__(384) void k_final(
    const float* __restrict__ x, const float* __restrict__ W_proj,
    float* __restrict__ out) {
  __shared__ float xs[384];
  int tk = blockIdx.x, t = threadIdx.x;
  xs[t] = x[tk * 384 + t];
  __syncthreads();
  float a0 = 0, a1 = 0, a2 = 0;
#pragma unroll 8
  for (int k = 0; k < 128; k++) {
    float w = W_proj[k * 384 + t];
    a0 += xs[k] * w; a1 += xs[128 + k] * w; a2 += xs[256 + k] * w;
  }
  a0 = fmaxf(a0, 0.f); a1 = fmaxf(a1, 0.f); a2 = fmaxf(a2, 0.f);
  out[98304 + (tk * 3 + 0) * 384 + t] = a0;
  out[98304 + (tk * 3 + 1) * 384 + t] = a1;
  out[98304 + (tk * 3 + 2) * 384 + t] = a2;
  out[tk * 384 + t] = (a0 + a1 + a2) * (1.f / 3.f);
}

// ---------------------------------------------------------------------------
extern "C" void kernel_launch(void* const* d_in, const int* in_sizes, int n_in,
                              void* d_out, int out_size, void* d_ws, size_t ws_size,
                              hipStream_t stream) {
  const float* ref_pos  = (const float*)d_in[0];
  const int*   uid      = (const int*)d_in[1];
  const float* r        = (const float*)d_in[2];
  const float* s        = (const float*)d_in[3];
  const float* z        = (const float*)d_in[4];
  const float* W_pos    = (const float*)d_in[5];
  const float* Wpo      = (const float*)d_in[6];
  const float* Wisd     = (const float*)d_in[7];
  const float* Wmask    = (const float*)d_in[8];
  const float* Wca      = (const float*)d_in[9];
  const float* Wcb      = (const float*)d_in[10];
  const float* ln_s_g   = (const float*)d_in[11];
  const float* ln_s_b   = (const float*)d_in[12];
  const float* W_single = (const float*)d_in[13];
  const float* ln_z_g   = (const float*)d_in[14];
  const float* ln_z_b   = (const float*)d_in[15];
  const float* W_pair   = (const float*)d_in[16];
  const float* W_noisy  = (const float*)d_in[17];
  const float* W_mlp1   = (const float*)d_in[18];
  const float* W_mlp2   = (const float*)d_in[19];
  const float* W_mlp3   = (const float*)d_in[20];
  const float* at_ln_g  = (const float*)d_in[21];
  const float* at_ln_b  = (const float*)d_in[22];
  const float* at_Wq    = (const float*)d_in[23];
  const float* at_Wk    = (const float*)d_in[24];
  const float* at_Wv    = (const float*)d_in[25];
  const float* at_Wg    = (const float*)d_in[26];
  const float* at_lnp_g = (const float*)d_in[27];
  const float* at_lnp_b = (const float*)d_in[28];
  const float* at_Wb    = (const float*)d_in[29];
  const float* at_Wo    = (const float*)d_in[30];
  const float* at_ln2_g = (const float*)d_in[31];
  const float* at_ln2_b = (const float*)d_in[32];
  const float* at_Wt1   = (const float*)d_in[33];
  const float* at_Wt2   = (const float*)d_in[34];
  const float* W_proj   = (const float*)d_in[35];
  float* out = (float*)d_out;
  float* W = (float*)d_ws;
  float* x     = W;                 //   98304
  float* ct    = W + 98304;         //   32768
  float* ca    = W + 131072;        //   12288
  float* cb    = W + 143360;        //   12288
  float* zp    = W + 155648;        // 1048576
  float* pnrm  = W + 1204224;       // 1572864
  float* biasA = W + 2777088;       // 1179648
  float* qkvg  = W + 3956736;       //  393216
  float* og    = W + 4349952;       //   98304  (total 4448256 f = 17.8 MB)

  k_tok<<<256, 128, 0, stream>>>(s, ln_s_g, ln_s_b, W_single, ct);
  k_atoms<<<768, 128, 0, stream>>>(ref_pos, r, ct, W_pos, W_noisy, Wca, Wcb,
                                   out + 393216, x, ca, cb);
  k_zp<<<4096, 256, 0, stream>>>(z, ln_z_g, ln_z_b, W_pair, zp);
  k_pair<<<2304, 256, 0, stream>>>(ref_pos, uid, Wpo, Wisd, Wmask, W_mlp1, W_mlp2,
                                   W_mlp3, zp, ca, cb, out + 491520, pnrm);
  k_bias<<<768, 128, 0, stream>>>(pnrm, at_lnp_g, at_lnp_b, at_Wb, biasA);
  for (int b = 0; b < 3; b++) {
    k_qkvg<<<384, 256, 0, stream>>>(x, at_ln_g + b * 128, at_ln_b + b * 128,
                                    at_Wq + b * 16384, at_Wk + b * 16384,
                                    at_Wv + b * 16384, at_Wg + b * 16384, qkvg);
    k_attn<<<96, 256, 0, stream>>>(qkvg, biasA + b * 393216, og);
    k_fused<<<96, 256, 0, stream>>>(og, at_Wo + b * 16384, at_ln2_g + b * 128,
                                    at_ln2_b + b * 128, at_Wt1 + b * 65536,
                                    at_Wt2 + b * 65536, x);
  }
  k_final<<<256, 384, 0, stream>>>(x, W_proj, out);
}

// Round 3
// 249.112 us; speedup vs baseline: 1.7531x; 1.3697x over previous
//
#include <hip/hip_runtime.h>
#include <math.h>

// N=768 atoms, T=256 tokens, CA=128, CP=16, CZ=128, CS=384, CT=384, H=4, DH=32
// d_out: a_out[256*384]@0, qout[768*384]@98304, c[768*128]@393216, pair[768*768*16]@491520

__device__ __forceinline__ float sigmoidf_(float v) { return 1.f / (1.f + __expf(-v)); }

// ---------------------------------------------------------------------------
// k_tokatoms: per token: SLN=LN(s); ctv = SLN@W_single (in reg). Then for the
// token's 3 atoms: c = c0+ctv; x = c0 + r@W_noisy; ca/cb = relu(c)@Wca/Wcb.
// grid 256, block 128
__global__ __launch_bounds__(128) void k_tokatoms(
    const float* __restrict__ s, const float* __restrict__ g,
    const float* __restrict__ b, const float* __restrict__ W_single,
    const float* __restrict__ ref_pos, const float* __restrict__ r,
    const float* __restrict__ W_pos, const float* __restrict__ W_noisy,
    const float* __restrict__ Wca, const float* __restrict__ Wcb,
    float* __restrict__ c_out, float* __restrict__ x,
    float* __restrict__ ca, float* __restrict__ cb) {
  int tok = blockIdx.x, t = threadIdx.x;
  __shared__ float sln[384];
  __shared__ float ws[48 * 128];
  __shared__ float red[4];
  __shared__ float rc[128];
  float v0 = s[tok * 384 + t], v1 = s[tok * 384 + 128 + t], v2 = s[tok * 384 + 256 + t];
  float ps = v0 + v1 + v2, pq = v0 * v0 + v1 * v1 + v2 * v2;
#pragma unroll
  for (int o = 1; o < 64; o <<= 1) { ps += __shfl_xor(ps, o); pq += __shfl_xor(pq, o); }
  if ((t & 63) == 0) { red[t >> 6] = ps; red[2 + (t >> 6)] = pq; }
  __syncthreads();
  float mean = (red[0] + red[1]) * (1.f / 384.f);
  float var = (red[2] + red[3]) * (1.f / 384.f) - mean * mean;
  float rstd = rsqrtf(var + 1e-5f);
  sln[t] = (v0 - mean) * rstd * g[t] + b[t];
  sln[128 + t] = (v1 - mean) * rstd * g[128 + t] + b[128 + t];
  sln[256 + t] = (v2 - mean) * rstd * g[256 + t] + b[256 + t];
  float ctv = 0.f;
  for (int c0 = 0; c0 < 384; c0 += 48) {
    __syncthreads();
#pragma unroll
    for (int m = 0; m < 12; m++) {
      int idx = (t + 128 * m) * 4;
      *(float4*)&ws[idx] = *(const float4*)&W_single[c0 * 128 + idx];
    }
    __syncthreads();
#pragma unroll 8
    for (int kk = 0; kk < 48; kk++) ctv += sln[c0 + kk] * ws[kk * 128 + t];
  }
  float wp0 = W_pos[t], wp1 = W_pos[128 + t], wp2 = W_pos[256 + t];
  float wn0 = W_noisy[t], wn1 = W_noisy[128 + t], wn2 = W_noisy[256 + t];
#pragma unroll
  for (int a = 0; a < 3; a++) {
    int i = tok + 256 * a;
    float p0 = ref_pos[i * 3], p1 = ref_pos[i * 3 + 1], p2 = ref_pos[i * 3 + 2];
    float r0 = r[i * 3], r1 = r[i * 3 + 1], r2 = r[i * 3 + 2];
    float c0 = p0 * wp0 + p1 * wp1 + p2 * wp2;
    x[i * 128 + t] = c0 + r0 * wn0 + r1 * wn1 + r2 * wn2;
    float cc = c0 + ctv;
    c_out[i * 128 + t] = cc;
    __syncthreads();
    rc[t] = fmaxf(cc, 0.f);
    __syncthreads();
    int out_id = t >> 2, q = t & 3;
    const float* Wm = (out_id < 16) ? Wca : Wcb;
    int ch = out_id & 15;
    float acc = 0.f;
#pragma unroll
    for (int kk = 0; kk < 32; kk++) { int k = q * 32 + kk; acc += rc[k] * Wm[k * 16 + ch]; }
    acc += __shfl_xor(acc, 1);
    acc += __shfl_xor(acc, 2);
    if (q == 0) { if (out_id < 16) ca[i * 16 + ch] = acc; else cb[i * 16 + ch] = acc; }
  }
}

// ---------------------------------------------------------------------------
// k_zp: zp[65536,16] = LN(z)@W_pair   grid 4096, block 256
__global__ __launch_bounds__(256) void k_zp(
    const float* __restrict__ z, const float* __restrict__ g,
    const float* __restrict__ lb, const float* __restrict__ W_pair,
    float* __restrict__ zp) {
  __shared__ float wT[16][132];
  __shared__ float zs[16][132];
  __shared__ float sWg[16], Bc[16];
  int t = threadIdx.x;
#pragma unroll
  for (int m = 0; m < 8; m++) {
    int e = t + 256 * m;
    int row = e >> 4, ch = e & 15;
    wT[ch][row] = g[row] * W_pair[e];
  }
  __syncthreads();
  if (t < 32) {
    int ch = t & 15;
    float a = 0.f;
    if (t < 16) {
#pragma unroll 8
      for (int k = 0; k < 128; k++) a += wT[ch][k];
      sWg[ch] = a;
    } else {
#pragma unroll 8
      for (int k = 0; k < 128; k++) a += lb[k] * W_pair[k * 16 + ch];
      Bc[ch] = a;
    }
  }
  int row = t >> 4, kk = (t & 15) * 8;
  long base = ((long)blockIdx.x * 16 + row) * 128 + kk;
  float4 a4 = *(const float4*)&z[base];
  float4 b4 = *(const float4*)&z[base + 4];
  *(float4*)&zs[row][kk] = a4;
  *(float4*)&zs[row][kk + 4] = b4;
  float ps = a4.x + a4.y + a4.z + a4.w + b4.x + b4.y + b4.z + b4.w;
  float pq = a4.x * a4.x + a4.y * a4.y + a4.z * a4.z + a4.w * a4.w +
             b4.x * b4.x + b4.y * b4.y + b4.z * b4.z + b4.w * b4.w;
#pragma unroll
  for (int o = 1; o < 16; o <<= 1) { ps += __shfl_xor(ps, o); pq += __shfl_xor(pq, o); }
  float m = ps * (1.f / 128.f);
  float rstd = rsqrtf(pq * (1.f / 128.f) - m * m + 1e-5f);
  __syncthreads();
  int ch = t & 15;
  float dotv = 0.f;
#pragma unroll 8
  for (int k4 = 0; k4 < 32; k4++) {
    float4 zv = *(float4*)&zs[row][k4 * 4];
    float4 wv = *(float4*)&wT[ch][k4 * 4];
    dotv += zv.x * wv.x + zv.y * wv.y + zv.z * wv.z + zv.w * wv.w;
  }
  zp[((long)blockIdx.x * 16 + row) * 16 + ch] = rstd * (dotv - m * sWg[ch]) + Bc[ch];
}

// ---------------------------------------------------------------------------
// k_pair: pair tensor + MLP (LDS b128 broadcast weights) + fused window bias
// for all 3 layers x 4 heads.  grid 2304 (i*3+jb), block 256 (one j each)
__global__ __launch_bounds__(256) void k_pair(
    const float* __restrict__ ref_pos, const int* __restrict__ uid,
    const float* __restrict__ Wpo, const float* __restrict__ Wisd,
    const float* __restrict__ Wmask, const float* __restrict__ W1,
    const float* __restrict__ W2, const float* __restrict__ W3,
    const float* __restrict__ zp, const float* __restrict__ ca,
    const float* __restrict__ cb, const float* __restrict__ lnp_g,
    const float* __restrict__ lnp_b, const float* __restrict__ Wb,
    float* __restrict__ pair_out, float* __restrict__ biasA) {
  int i = blockIdx.x / 3, jb = blockIdx.x % 3, t = threadIdx.x;
  int j = jb * 256 + t;
  __shared__ float w1s[256], w2s[256], w3s[256];
  __shared__ float wpo[48], wisd[16], wmask[16], cai[16];
  __shared__ float wgb[192];  // [b][k][h]
  __shared__ float kbs[12];   // [b][h]
  w1s[t] = W1[t]; w2s[t] = W2[t]; w3s[t] = W3[t];
  if (t < 48) wpo[t] = Wpo[t];
  if (t < 16) { wisd[t] = Wisd[t]; wmask[t] = Wmask[t]; cai[t] = ca[i * 16 + t]; }
  if (t >= 64) {
    int e = t - 64;
    int bq = e >> 6, k = (e >> 2) & 15, h = e & 3;
    wgb[e] = lnp_g[bq * 16 + k] * Wb[bq * 64 + k * 4 + h];
  }
  if (t >= 48 && t < 60) {
    int e = t - 48, bq = e >> 2, h = e & 3;
    float a = 0.f;
#pragma unroll
    for (int c = 0; c < 16; c++) a += lnp_b[bq * 16 + c] * Wb[bq * 64 + c * 4 + h];
    kbs[e] = a;
  }
  __syncthreads();
  float d0 = ref_pos[i * 3] - ref_pos[j * 3];
  float d1 = ref_pos[i * 3 + 1] - ref_pos[j * 3 + 1];
  float d2 = ref_pos[i * 3 + 2] - ref_pos[j * 3 + 2];
  float mask = (uid[i] == uid[j]) ? 1.f : 0.f;
  float inv = 1.f / (1.f + d0 * d0 + d1 * d1 + d2 * d2);
  const float4* zpv = (const float4*)&zp[(((i & 255) << 8) + t) * 16];
  const float4* cbv = (const float4*)&cb[j * 16];
  float p[16];
#pragma unroll
  for (int q = 0; q < 4; q++) {
    float4 zv = zpv[q];
    float4 bv = cbv[q];
    float4 w0 = *(float4*)&wpo[q * 4];
    float4 w1 = *(float4*)&wpo[16 + q * 4];
    float4 w2 = *(float4*)&wpo[32 + q * 4];
    float4 wi = *(float4*)&wisd[q * 4];
    float4 wm = *(float4*)&wmask[q * 4];
    float4 cv = *(float4*)&cai[q * 4];
    p[q * 4 + 0] = mask * (d0 * w0.x + d1 * w1.x + d2 * w2.x + inv * wi.x + wm.x) + zv.x + bv.x + cv.x;
    p[q * 4 + 1] = mask * (d0 * w0.y + d1 * w1.y + d2 * w2.y + inv * wi.y + wm.y) + zv.y + bv.y + cv.y;
    p[q * 4 + 2] = mask * (d0 * w0.z + d1 * w1.z + d2 * w2.z + inv * wi.z + wm.z) + zv.z + bv.z + cv.z;
    p[q * 4 + 3] = mask * (d0 * w0.w + d1 * w1.w + d2 * w2.w + inv * wi.w + wm.w) + zv.w + bv.w + cv.w;
  }
  float cur[16], nxt[16];
#pragma unroll
  for (int c = 0; c < 16; c++) cur[c] = fmaxf(p[c], 0.f);
#pragma unroll
  for (int c = 0; c < 16; c++) nxt[c] = 0.f;
#pragma unroll
  for (int k = 0; k < 16; k++) {
    float tv = cur[k];
#pragma unroll
    for (int q = 0; q < 4; q++) {
      float4 w = *(float4*)&w1s[k * 16 + q * 4];
      nxt[q * 4 + 0] += tv * w.x; nxt[q * 4 + 1] += tv * w.y;
      nxt[q * 4 + 2] += tv * w.z; nxt[q * 4 + 3] += tv * w.w;
    }
  }
#pragma unroll
  for (int c = 0; c < 16; c++) { cur[c] = fmaxf(nxt[c], 0.f); nxt[c] = 0.f; }
#pragma unroll
  for (int k = 0; k < 16; k++) {
    float tv = cur[k];
#pragma unroll
    for (int q = 0; q < 4; q++) {
      float4 w = *(float4*)&w2s[k * 16 + q * 4];
      nxt[q * 4 + 0] += tv * w.x; nxt[q * 4 + 1] += tv * w.y;
      nxt[q * 4 + 2] += tv * w.z; nxt[q * 4 + 3] += tv * w.w;
    }
  }
#pragma unroll
  for (int c = 0; c < 16; c++) { cur[c] = fmaxf(nxt[c], 0.f); nxt[c] = p[c]; }
#pragma unroll
  for (int k = 0; k < 16; k++) {
    float tv = cur[k];
#pragma unroll
    for (int q = 0; q < 4; q++) {
      float4 w = *(float4*)&w3s[k * 16 + q * 4];
      nxt[q * 4 + 0] += tv * w.x; nxt[q * 4 + 1] += tv * w.y;
      nxt[q * 4 + 2] += tv * w.z; nxt[q * 4 + 3] += tv * w.w;
    }
  }
  // nxt == pf (final pair values)
  long po = ((long)i * 768 + j) * 16;
  float4 s0 = {nxt[0], nxt[1], nxt[2], nxt[3]};
  float4 s1 = {nxt[4], nxt[5], nxt[6], nxt[7]};
  float4 s2 = {nxt[8], nxt[9], nxt[10], nxt[11]};
  float4 s3 = {nxt[12], nxt[13], nxt[14], nxt[15]};
  *(float4*)&pair_out[po] = s0;
  *(float4*)&pair_out[po + 4] = s1;
  *(float4*)&pair_out[po + 8] = s2;
  *(float4*)&pair_out[po + 12] = s3;
  int qb = i >> 5, qi = i & 31;
  int lo = qb * 32 - 48;
  int jw = j - lo;
  if ((unsigned)jw < 128u) {
    float m = 0.f;
#pragma unroll
    for (int c = 0; c < 16; c++) m += nxt[c];
    m *= (1.f / 16.f);
    float vv = 0.f;
#pragma unroll
    for (int c = 0; c < 16; c++) { float d = nxt[c] - m; vv += d * d; }
    float rs = rsqrtf(vv * (1.f / 16.f) + 1e-5f);
#pragma unroll
    for (int c = 0; c < 16; c++) cur[c] = (nxt[c] - m) * rs;  // nrm
#pragma unroll
    for (int bq = 0; bq < 3; bq++) {
      float o0 = kbs[bq * 4 + 0], o1 = kbs[bq * 4 + 1];
      float o2 = kbs[bq * 4 + 2], o3 = kbs[bq * 4 + 3];
#pragma unroll
      for (int k = 0; k < 16; k++) {
        float nv = cur[k];
        float4 w = *(float4*)&wgb[bq * 64 + k * 4];
        o0 += nv * w.x; o1 += nv * w.y; o2 += nv * w.z; o3 += nv * w.w;
      }
      long base = (long)(bq * 96 + qb * 4) * 4096 + (long)qi * 128 + jw;
      biasA[base] = o0;
      biasA[base + 4096] = o1;
      biasA[base + 2 * 4096] = o2;
      biasA[base + 3 * 4096] = o3;
    }
  }
}

// ---------------------------------------------------------------------------
// k_qkvg: a=LN(x); tile GEMM into qkvg[768,512].  grid 384 (rb*8+bn), block 256
__global__ __launch_bounds__(256) void k_qkvg(
    const float* __restrict__ x, const float* __restrict__ lng,
    const float* __restrict__ lnb, const float* __restrict__ Wq,
    const float* __restrict__ Wk, const float* __restrict__ Wv,
    const float* __restrict__ Wg, float* __restrict__ qkvg) {
  __shared__ float As[128][18];
  __shared__ float Ws[128][66];
  int t = threadIdx.x;
  int rb = blockIdx.x >> 3, bn = blockIdx.x & 7;
  int r0 = rb * 16;
  const float* Wm = (bn < 2) ? Wq : (bn < 4) ? Wk : (bn < 6) ? Wv : Wg;
  int c0 = (bn & 1) * 64;
  int ncol0 = (bn >> 1) * 128 + c0;
#pragma unroll
  for (int m = 0; m < 8; m++) {
    int idx = t + 256 * m;
    int row = idx >> 4, c4 = (idx & 15) * 4;
    *(float4*)&Ws[row][c4] = *(const float4*)&Wm[row * 128 + c0 + c4];
  }
  {
    int rr = t >> 4, tt = t & 15;
    int row = r0 + rr;
    float4 x0 = *(const float4*)&x[row * 128 + tt * 8];
    float4 x1 = *(const float4*)&x[row * 128 + tt * 8 + 4];
    float ps = x0.x + x0.y + x0.z + x0.w + x1.x + x1.y + x1.z + x1.w;
    float pq = x0.x * x0.x + x0.y * x0.y + x0.z * x0.z + x0.w * x0.w +
               x1.x * x1.x + x1.y * x1.y + x1.z * x1.z + x1.w * x1.w;
#pragma unroll
    for (int o = 1; o < 16; o <<= 1) { ps += __shfl_xor(ps, o); pq += __shfl_xor(pq, o); }
    float m = ps * (1.f / 128.f);
    float rstd = rsqrtf(pq * (1.f / 128.f) - m * m + 1e-5f);
    float4 g0 = *(const float4*)&lng[tt * 8], g1 = *(const float4*)&lng[tt * 8 + 4];
    float4 b0 = *(const float4*)&lnb[tt * 8], b1 = *(const float4*)&lnb[tt * 8 + 4];
    As[tt * 8 + 0][rr] = (x0.x - m) * rstd * g0.x + b0.x;
    As[tt * 8 + 1][rr] = (x0.y - m) * rstd * g0.y + b0.y;
    As[tt * 8 + 2][rr] = (x0.z - m) * rstd * g0.z + b0.z;
    As[tt * 8 + 3][rr] = (x0.w - m) * rstd * g0.w + b0.w;
    As[tt * 8 + 4][rr] = (x1.x - m) * rstd * g1.x + b1.x;
    As[tt * 8 + 5][rr] = (x1.y - m) * rstd * g1.y + b1.y;
    As[tt * 8 + 6][rr] = (x1.z - m) * rstd * g1.z + b1.z;
    As[tt * 8 + 7][rr] = (x1.w - m) * rstd * g1.w + b1.w;
  }
  __syncthreads();
  int ty = t >> 5, tx = t & 31;
  float a00 = 0, a01 = 0, a10 = 0, a11 = 0;
#pragma unroll 8
  for (int k = 0; k < 128; k++) {
    float2 a2 = *(float2*)&As[k][ty * 2];
    float2 w2 = *(float2*)&Ws[k][tx * 2];
    a00 += a2.x * w2.x; a01 += a2.x * w2.y;
    a10 += a2.y * w2.x; a11 += a2.y * w2.y;
  }
  int row = r0 + ty * 2;
  float2 o0 = {a00, a01}, o1 = {a10, a11};
  *(float2*)&qkvg[row * 512 + ncol0 + tx * 2] = o0;
  *(float2*)&qkvg[(row + 1) * 512 + ncol0 + tx * 2] = o1;
}

// ---------------------------------------------------------------------------
// k_attn: windowed attention per (qb,h); OOB bias filled inline.  grid 96, block 256
__global__ __launch_bounds__(256) void k_attn(
    const float* __restrict__ qkvg, const float* __restrict__ biasb,
    float* __restrict__ og) {
  int qb = blockIdx.x >> 2, h = blockIdx.x & 3, t = threadIdx.x;
  int i0 = qb * 32, lo = i0 - 48;
  __shared__ float qs[32][36];
  __shared__ float ks[128][36];
  __shared__ float vs[128][36];
  __shared__ float L[32][132];
#pragma unroll
  for (int m = 0; m < 4; m++) {
    int idx = t + 256 * m;
    int qi = idx >> 5, k4 = (idx & 31) * 4;
    int j = lo + k4;
    float4 bv;
    if (j >= 0 && j < 768) bv = *(const float4*)&biasb[(qb * 4 + h) * 4096 + qi * 128 + k4];
    else bv = make_float4(-1e30f, -1e30f, -1e30f, -1e30f);
    *(float4*)&L[qi][k4] = bv;
  }
  {
    int qi = t >> 3, dq = (t & 7) * 4;
    *(float4*)&qs[qi][dq] = *(const float4*)&qkvg[(i0 + qi) * 512 + h * 32 + dq];
  }
  {
    int kj = t >> 1, dh = (t & 1) * 16;
    int j = lo + kj;
    if (j >= 0 && j < 768) {
      const float4* sk = (const float4*)&qkvg[j * 512 + 128 + h * 32 + dh];
      const float4* sv = (const float4*)&qkvg[j * 512 + 256 + h * 32 + dh];
#pragma unroll
      for (int m = 0; m < 4; m++) {
        *(float4*)&ks[kj][dh + 4 * m] = sk[m];
        *(float4*)&vs[kj][dh + 4 * m] = sv[m];
      }
    } else {
      float4 zz = {0, 0, 0, 0};
#pragma unroll
      for (int m = 0; m < 4; m++) {
        *(float4*)&ks[kj][dh + 4 * m] = zz;
        *(float4*)&vs[kj][dh + 4 * m] = zz;
      }
    }
  }
  __syncthreads();
  const float scale = 0.17677669529663687f;
  {
    int qi = t & 31, kb = t >> 5;
    float4 qr[8];
#pragma unroll
    for (int m = 0; m < 8; m++) qr[m] = *(float4*)&qs[qi][m * 4];
#pragma unroll 2
    for (int kk = 0; kk < 16; kk++) {
      int kj = kb * 16 + kk;
      float acc = 0.f;
#pragma unroll
      for (int m = 0; m < 8; m++) {
        float4 kv = *(float4*)&ks[kj][m * 4];
        acc += qr[m].x * kv.x + qr[m].y * kv.y + qr[m].z * kv.z + qr[m].w * kv.w;
      }
      L[qi][kj] += acc * scale;
    }
  }
  __syncthreads();
  int qi = t >> 3, sg = t & 7;
  float mx = -1e30f;
#pragma unroll
  for (int k2 = 0; k2 < 16; k2++) mx = fmaxf(mx, L[qi][sg * 16 + k2]);
#pragma unroll
  for (int o = 1; o < 8; o <<= 1) mx = fmaxf(mx, __shfl_xor(mx, o));
  float sum = 0.f;
#pragma unroll
  for (int k2 = 0; k2 < 16; k2++) {
    int kj = sg * 16 + k2;
    float e = __expf(L[qi][kj] - mx);
    L[qi][kj] = e;
    sum += e;
  }
#pragma unroll
  for (int o = 1; o < 8; o <<= 1) sum += __shfl_xor(sum, o);
  float rden = 1.f / sum;
  __syncthreads();
  int d0 = (t & 7) * 4;
  float4 acc = {0, 0, 0, 0};
#pragma unroll 4
  for (int kj = 0; kj < 128; kj++) {
    float p = L[qi][kj];
    float4 v = *(const float4*)&vs[kj][d0];
    acc.x += p * v.x; acc.y += p * v.y; acc.z += p * v.z; acc.w += p * v.w;
  }
  int i = i0 + qi;
  float4 gr = *(const float4*)&qkvg[i * 512 + 384 + h * 32 + d0];
  float4 o4;
  o4.x = acc.x * rden * sigmoidf_(gr.x);
  o4.y = acc.y * rden * sigmoidf_(gr.y);
  o4.z = acc.z * rden * sigmoidf_(gr.z);
  o4.w = acc.w * rden * sigmoidf_(gr.w);
  *(float4*)&og[i * 128 + h * 32 + d0] = o4;
}

// ---------------------------------------------------------------------------
// k_fused: x += og@Wo; t=LN(x); x += relu(t@Wt1)@Wt2.  grid 96 (8 rows), block 256
__global__ __launch_bounds__(256) void k_fused(
    const float* __restrict__ og, const float* __restrict__ Wo,
    const float* __restrict__ g2, const float* __restrict__ b2,
    const float* __restrict__ Wt1, const float* __restrict__ Wt2,
    float* __restrict__ x) {
  int t = threadIdx.x;
  int r0 = blockIdx.x * 8;
  __shared__ float os[8][132];
  __shared__ float xn[8][132];
  __shared__ float a[8][132];
  __shared__ float h[8][516];
  __shared__ float wc[8192];
  {
    int rr = t >> 5, c4 = (t & 31) * 4;
    *(float4*)&os[rr][c4] = *(const float4*)&og[(r0 + rr) * 128 + c4];
    *(float4*)&xn[rr][c4] = *(const float4*)&x[(r0 + rr) * 128 + c4];
  }
  int c = t & 127, rh = t >> 7;
  float ac[4] = {0, 0, 0, 0};
  for (int k0 = 0; k0 < 128; k0 += 64) {
    __syncthreads();
#pragma unroll
    for (int m = 0; m < 8; m++) {
      int idx = (t + 256 * m) * 4;
      *(float4*)&wc[idx] = *(const float4*)&Wo[k0 * 128 + idx];
    }
    __syncthreads();
#pragma unroll 4
    for (int kk = 0; kk < 64; kk++) {
      float w = wc[kk * 128 + c];
      int k = k0 + kk;
      ac[0] += os[rh * 4 + 0][k] * w; ac[1] += os[rh * 4 + 1][k] * w;
      ac[2] += os[rh * 4 + 2][k] * w; ac[3] += os[rh * 4 + 3][k] * w;
    }
  }
  __syncthreads();
#pragma unroll
  for (int rr = 0; rr < 4; rr++) xn[rh * 4 + rr][c] += ac[rr];
  __syncthreads();
  {
    int rr = t >> 5, tt = t & 31;
    float4 xv = *(float4*)&xn[rr][tt * 4];
    float ps = xv.x + xv.y + xv.z + xv.w;
    float pq = xv.x * xv.x + xv.y * xv.y + xv.z * xv.z + xv.w * xv.w;
#pragma unroll
    for (int o = 1; o < 32; o <<= 1) { ps += __shfl_xor(ps, o); pq += __shfl_xor(pq, o); }
    float m = ps * (1.f / 128.f);
    float rstd = rsqrtf(pq * (1.f / 128.f) - m * m + 1e-5f);
    float4 gg = *(const float4*)&g2[tt * 4];
    float4 bb = *(const float4*)&b2[tt * 4];
    float4 av;
    av.x = (xv.x - m) * rstd * gg.x + bb.x;
    av.y = (xv.y - m) * rstd * gg.y + bb.y;
    av.z = (xv.z - m) * rstd * gg.z + bb.z;
    av.w = (xv.w - m) * rstd * gg.w + bb.w;
    *(float4*)&a[rr][tt * 4] = av;
  }
  int rr3 = t >> 5, cg = t & 31;
  float acc16[16];
#pragma unroll
  for (int e = 0; e < 16; e++) acc16[e] = 0.f;
  for (int k0 = 0; k0 < 128; k0 += 16) {
    __syncthreads();
#pragma unroll
    for (int m = 0; m < 8; m++) {
      int idx = (t + 256 * m) * 4;
      *(float4*)&wc[idx] = *(const float4*)&Wt1[k0 * 512 + idx];
    }
    __syncthreads();
#pragma unroll 2
    for (int kk = 0; kk < 16; kk++) {
      float av = a[rr3][k0 + kk];
#pragma unroll
      for (int q = 0; q < 4; q++) {
        float4 w4 = *(float4*)&wc[kk * 512 + q * 128 + cg * 4];
        acc16[q * 4 + 0] += av * w4.x; acc16[q * 4 + 1] += av * w4.y;
        acc16[q * 4 + 2] += av * w4.z; acc16[q * 4 + 3] += av * w4.w;
      }
    }
  }
  __syncthreads();
#pragma unroll
  for (int q = 0; q < 4; q++) {
    float4 hv = {fmaxf(acc16[q * 4 + 0], 0.f), fmaxf(acc16[q * 4 + 1], 0.f),
                 fmaxf(acc16[q * 4 + 2], 0.f), fmaxf(acc16[q * 4 + 3], 0.f)};
    *(float4*)&h[rr3][q * 128 + cg * 4] = hv;
  }
  float ac2[4] = {0, 0, 0, 0};
  for (int k0 = 0; k0 < 512; k0 += 64) {
    __syncthreads();
#pragma unroll
    for (int m = 0; m < 8; m++) {
      int idx = (t + 256 * m) * 4;
      *(float4*)&wc[idx] = *(const float4*)&Wt2[k0 * 128 + idx];
    }
    __syncthreads();
#pragma unroll 4
    for (int kk = 0; kk < 64; kk++) {
      float w = wc[kk * 128 + c];
      int k = k0 + kk;
      ac2[0] += h[rh * 4 + 0][k] * w; ac2[1] += h[rh * 4 + 1][k] * w;
      ac2[2] += h[rh * 4 + 2][k] * w; ac2[3] += h[rh * 4 + 3][k] * w;
    }
  }
#pragma unroll
  for (int rr = 0; rr < 4; rr++)
    x[(r0 + rh * 4 + rr) * 128 + c] = xn[rh * 4 + rr][c] + ac2[rr];
}

// ---------------------------------------------------------------------------
// k_final: qout = relu(x@W_proj); a_out = mean over 3 atoms  grid 256, block 384
__global__ __launch_bounds__(384) void k_final(
    const float* __restrict__ x, const float* __restrict__ W_proj,
    float* __restrict__ out) {
  __shared__ float xs[384];
  int tk = blockIdx.x, t = threadIdx.x;
  xs[t] = x[tk * 384 + t];
  __syncthreads();
  float a0 = 0, a1 = 0, a2 = 0;
#pragma unroll 8
  for (int k = 0; k < 128; k++) {
    float w = W_proj[k * 384 + t];
    a0 += xs[k] * w; a1 += xs[128 + k] * w; a2 += xs[256 + k] * w;
  }
  a0 = fmaxf(a0, 0.f); a1 = fmaxf(a1, 0.f); a2 = fmaxf(a2, 0.f);
  out[98304 + (tk * 3 + 0) * 384 + t] = a0;
  out[98304 + (tk * 3 + 1) * 384 + t] = a1;
  out[98304 + (tk * 3 + 2) * 384 + t] = a2;
  out[tk * 384 + t] = (a0 + a1 + a2) * (1.f / 3.f);
}

// ---------------------------------------------------------------------------
extern "C" void kernel_launch(void* const* d_in, const int* in_sizes, int n_in,
                              void* d_out, int out_size, void* d_ws, size_t ws_size,
                              hipStream_t stream) {
  const float* ref_pos  = (const float*)d_in[0];
  const int*   uid      = (const int*)d_in[1];
  const float* r        = (const float*)d_in[2];
  const float* s        = (const float*)d_in[3];
  const float* z        = (const float*)d_in[4];
  const float* W_pos    = (const float*)d_in[5];
  const float* Wpo      = (const float*)d_in[6];
  const float* Wisd     = (const float*)d_in[7];
  const float* Wmask    = (const float*)d_in[8];
  const float* Wca      = (const float*)d_in[9];
  const float* Wcb      = (const float*)d_in[10];
  const float* ln_s_g   = (const float*)d_in[11];
  const float* ln_s_b   = (const float*)d_in[12];
  const float* W_single = (const float*)d_in[13];
  const float* ln_z_g   = (const float*)d_in[14];
  const float* ln_z_b   = (const float*)d_in[15];
  const float* W_pair   = (const float*)d_in[16];
  const float* W_noisy  = (const float*)d_in[17];
  const float* W_mlp1   = (const float*)d_in[18];
  const float* W_mlp2   = (const float*)d_in[19];
  const float* W_mlp3   = (const float*)d_in[20];
  const float* at_ln_g  = (const float*)d_in[21];
  const float* at_ln_b  = (const float*)d_in[22];
  const float* at_Wq    = (const float*)d_in[23];
  const float* at_Wk    = (const float*)d_in[24];
  const float* at_Wv    = (const float*)d_in[25];
  const float* at_Wg    = (const float*)d_in[26];
  const float* at_lnp_g = (const float*)d_in[27];
  const float* at_lnp_b = (const float*)d_in[28];
  const float* at_Wb    = (const float*)d_in[29];
  const float* at_Wo    = (const float*)d_in[30];
  const float* at_ln2_g = (const float*)d_in[31];
  const float* at_ln2_b = (const float*)d_in[32];
  const float* at_Wt1   = (const float*)d_in[33];
  const float* at_Wt2   = (const float*)d_in[34];
  const float* W_proj   = (const float*)d_in[35];
  float* out = (float*)d_out;
  float* W = (float*)d_ws;
  float* x     = W;                 //   98304
  float* ca    = W + 98304;         //   12288
  float* cb    = W + 110592;        //   12288
  float* zp    = W + 122880;        // 1048576
  float* biasA = W + 1171456;       // 1179648
  float* qkvg  = W + 2351104;       //  393216
  float* og    = W + 2744320;       //   98304  (total 2842624 f = 11.4 MB)

  k_zp<<<4096, 256, 0, stream>>>(z, ln_z_g, ln_z_b, W_pair, zp);
  k_tokatoms<<<256, 128, 0, stream>>>(s, ln_s_g, ln_s_b, W_single, ref_pos, r,
                                      W_pos, W_noisy, Wca, Wcb,
                                      out + 393216, x, ca, cb);
  k_pair<<<2304, 256, 0, stream>>>(ref_pos, uid, Wpo, Wisd, Wmask, W_mlp1, W_mlp2,
                                   W_mlp3, zp, ca, cb, at_lnp_g, at_lnp_b, at_Wb,
                                   out + 491520, biasA);
  for (int b = 0; b < 3; b++) {
    k_qkvg<<<384, 256, 0, stream>>>(x, at_ln_g + b * 128, at_ln_b + b * 128,
                                    at_Wq + b * 16384, at_Wk + b * 16384,
                                    at_Wv + b * 16384, at_Wg + b * 16384, qkvg);
    k_attn<<<96, 256, 0, stream>>>(qkvg, biasA + b * 393216, og);
    k_fused<<<96, 256, 0, stream>>>(og, at_Wo + b * 16384, at_ln2_g + b * 128,
                                    at_ln2_b + b * 128, at_Wt1 + b * 65536,
                                    at_Wt2 + b * 65536, x);
  }
  k_final<<<256, 384, 0, stream>>>(x, W_proj, out);
}